// Round 17
// baseline (151.310 us; speedup 1.0000x reference)
//
#include <hip/hip_runtime.h>

// Problem constants (B,S,H,D fixed by the reference)
#define BB   2
#define SS   2048
#define HH   16
#define DD   64
#define CC   128               // chunk length
#define NCH  (SS/CC)           // 16 chunks per (b,h)
#define RECF (DD*DD + DD)      // 4160 elems per record: State^T rows 0..63 + ksum row 64
#define BHN  (BB*HH)           // 32
#define NCHK (BHN*NCH)         // 512 chunk-blocks

typedef __attribute__((ext_vector_type(8))) short short8;
typedef __attribute__((ext_vector_type(4))) float f32x4;

// XOR swizzle of the s-index (units of 8 shorts) by LDS row (stride-136 tiles).
#define SW(r) ((((r) >> 3) & 7) << 3)
// XOR swizzle for the pad-free Kbh[64][64] tile in k_out.
#define SK(r) (((r) & 7) << 3)

__device__ __forceinline__ float elu1(float x) {
    return x > 0.0f ? x + 1.0f : __expf(x);
}
__device__ __forceinline__ short f2bf(float f) {
    union { float f; unsigned u; } x; x.f = f;
    unsigned r = x.u + 0x7FFFu + ((x.u >> 16) & 1u);   // RNE
    return (short)(r >> 16);
}
__device__ __forceinline__ float bf2f(short s) {
    union { unsigned u; float f; } x; x.u = ((unsigned)(unsigned short)s) << 16;
    return x.f;
}
// pack two bf16 into one dword: lo -> short[0], hi -> short[1]
__device__ __forceinline__ unsigned pack2(float lo, float hi) {
    return (unsigned)(unsigned short)f2bf(lo)
         | ((unsigned)(unsigned short)f2bf(hi) << 16);
}

// ---------------------------------------------------------------------------
// Kernel 1 (R15 k_state + fused scan tail): per-chunk State^T (+ksum row)
// = [V^T; ones] . K -> rec_g. The LAST block per bh (device-scope atomic
// counter; no spinning) performs the 16-chunk exclusive scan -> stp_g,
// with the identical ascending-order fp32 arithmetic as the old k_scan.
// ---------------------------------------------------------------------------
__global__ __launch_bounds__(512) void k_state(const float* __restrict__ qk,
                                               const float* __restrict__ v,
                                               short* __restrict__ rec_g,
                                               short* __restrict__ stp_g,
                                               int* __restrict__ cnt) {
    const int blk = blockIdx.x;
    const int c   = blk % NCH;
    const int bh  = blk / NCH;
    const int b = bh / HH, h = bh % HH;
    const int tid = threadIdx.x;
    const int w   = tid >> 6;
    const int l   = tid & 63;
    const int l15 = l & 15;
    const int g   = l >> 4;

    __shared__ short KT[64][136];   // K^T, swizzled cols
    __shared__ short VT[65][136];   // V^T + ones row 64

#pragma unroll
    for (int it = 0; it < 2; ++it) {
        const int pi   = tid + it*512;      // 0..1023
        const int r    = pi >> 4;           // row-pair index
        const int col4 = (pi & 15) * 4;     // d base
        const int s0 = c*CC + 2*r;
        const float* kp = qk + ((((size_t)b*SS + s0)*2 + 1)*HH + h)*DD + col4;
        float4 k0 = *(const float4*)kp;
        float4 k1 = *(const float4*)(kp + 2*HH*DD);
        const float* vp = v + (((size_t)b*SS + s0)*HH + h)*DD + col4;
        float4 v0 = *(const float4*)vp;
        float4 v1 = *(const float4*)(vp + HH*DD);
        const int s2 = 2*r;
        *(unsigned*)(&KT[col4+0][s2 ^ SW(col4+0)]) = pack2(elu1(k0.x), elu1(k1.x));
        *(unsigned*)(&KT[col4+1][s2 ^ SW(col4+1)]) = pack2(elu1(k0.y), elu1(k1.y));
        *(unsigned*)(&KT[col4+2][s2 ^ SW(col4+2)]) = pack2(elu1(k0.z), elu1(k1.z));
        *(unsigned*)(&KT[col4+3][s2 ^ SW(col4+3)]) = pack2(elu1(k0.w), elu1(k1.w));
        *(unsigned*)(&VT[col4+0][s2 ^ SW(col4+0)]) = pack2(v0.x, v1.x);
        *(unsigned*)(&VT[col4+1][s2 ^ SW(col4+1)]) = pack2(v0.y, v1.y);
        *(unsigned*)(&VT[col4+2][s2 ^ SW(col4+2)]) = pack2(v0.z, v1.z);
        *(unsigned*)(&VT[col4+3][s2 ^ SW(col4+3)]) = pack2(v0.w, v1.w);
    }
    if (tid < 64) *(unsigned*)(&VT[64][2*tid]) = 0x3F803F80u;   // ones row (SW(64)==0)
    __syncthreads();

    const int dtile = w & 3;
    const int half  = w >> 2;
    const int nrt   = half ? 2 : 3;
    const int rt0   = half ? 3 : 0;
    f32x4 acc1[3];
#pragma unroll
    for (int i = 0; i < 3; ++i) acc1[i] = (f32x4){0.f,0.f,0.f,0.f};
    const int krow = 16*dtile + l15;
#pragma unroll
    for (int ks = 0; ks < 4; ++ks) {
        const int cb = 32*ks + 8*g;
        short8 bk = *(const short8*)(&KT[krow][cb ^ SW(krow)]);
#pragma unroll
        for (int i = 0; i < 3; ++i) {
            if (i < nrt) {
                int arow = 16*(rt0 + i) + l15;
                if (arow > 64) arow = 64;          // clamp into ones row
                short8 a = *(const short8*)(&VT[arow][cb ^ SW(arow)]);
                acc1[i] = __builtin_amdgcn_mfma_f32_16x16x32_bf16(a, bk, acc1[i], 0, 0, 0);
            }
        }
    }
    short* rec = rec_g + (size_t)blk * RECF;
#pragma unroll
    for (int i = 0; i < 3; ++i) {
        if (i < nrt) {
            const int rt = rt0 + i;
            if (rt < 4) {
#pragma unroll
                for (int e = 0; e < 4; ++e)
                    rec[(16*rt + 4*g + e)*DD + 16*dtile + l15] = f2bf(acc1[i][e]);
            } else if (g == 0) {
                rec[4096 + 16*dtile + l15] = f2bf(acc1[i][0]);   // ksum row
            }
        }
    }

    // ---- fused scan tail: last block per bh does the exclusive scan ----
    __threadfence();               // device-scope: rec visible before count
    __syncthreads();               // all threads' stores + fences done
    __shared__ int amLast;
    if (tid == 0) {
        const int prev = __hip_atomic_fetch_add(&cnt[bh], 1, __ATOMIC_ACQ_REL,
                                                __HIP_MEMORY_SCOPE_AGENT);
        amLast = (prev == NCH - 1);
    }
    __syncthreads();
    if (amLast) {
        const short* rb = rec_g + (size_t)(bh*NCH) * RECF;
        short*       sb = stp_g + (size_t)(bh*NCH) * RECF;
#pragma unroll 1
        for (int elem = tid; elem < RECF; elem += 512) {
            float vals[16];
#pragma unroll
            for (int c2 = 0; c2 < 16; ++c2)
                vals[c2] = bf2f(rb[(size_t)c2*RECF + elem]);
            float pref = 0.0f;
#pragma unroll
            for (int c2 = 0; c2 < 16; ++c2) {
                sb[(size_t)c2*RECF + elem] = f2bf(pref);
                pref += vals[c2];
            }
        }
    }
}

// ---------------------------------------------------------------------------
// Kernel 2 (verbatim R15 k_out): O = [S | Q] . [V;ones ; State_prefix^T;ksum].
// Half-K tile staged twice; LDS 53,664 B. No launch-bounds min.
// ---------------------------------------------------------------------------
__global__ __launch_bounds__(512) void k_out(const float* __restrict__ qk,
                                             const float* __restrict__ v,
                                             const short* __restrict__ stp_g,
                                             float* __restrict__ out) {
    const int blk = blockIdx.x;
    const int c   = blk % NCH;
    const int bh  = blk / NCH;
    const int b = bh / HH, h = bh % HH;
    const int tid = threadIdx.x;
    const int w   = tid >> 6;
    const int l   = tid & 63;
    const int l15 = l & 15;
    const int g   = l >> 4;

    __shared__ short Kbh[64][64];   // half K tile, XOR-swizzled   8192 B
    __shared__ short Sbh[128][72];  // score half (two passes)    18432 B
    __shared__ short StT[65][72];   // prefix State^T + ksum row   9360 B
    __shared__ short VT[65][136];   // V^T + ones row 64          17680 B

    // ---- V staging: packed row-pair dword transpose ----
#pragma unroll
    for (int it = 0; it < 2; ++it) {
        const int pi   = tid + it*512;      // 0..1023
        const int r    = pi >> 4;
        const int col4 = (pi & 15) * 4;
        const int s0 = c*CC + 2*r;
        const float* vp = v + (((size_t)b*SS + s0)*HH + h)*DD + col4;
        float4 v0 = *(const float4*)vp;
        float4 v1 = *(const float4*)(vp + HH*DD);
        const int s2 = 2*r;
        *(unsigned*)(&VT[col4+0][s2 ^ SW(col4+0)]) = pack2(v0.x, v1.x);
        *(unsigned*)(&VT[col4+1][s2 ^ SW(col4+1)]) = pack2(v0.y, v1.y);
        *(unsigned*)(&VT[col4+2][s2 ^ SW(col4+2)]) = pack2(v0.z, v1.z);
        *(unsigned*)(&VT[col4+3][s2 ^ SW(col4+3)]) = pack2(v0.w, v1.w);
    }
    if (tid < 64) *(unsigned*)(&VT[64][2*tid]) = 0x3F803F80u;   // ones row

    // ---- Kbh pass-A staging (K rows 0..63) ----
#pragma unroll
    for (int it = 0; it < 2; ++it) {
        const int f    = tid + it*512;      // 0..1023
        const int row  = f >> 4;            // 0..63
        const int col4 = (f & 15) * 4;
        const int s = c*CC + row;
        float4 kq = *(const float4*)(qk + ((((size_t)b*SS + s)*2 + 1)*HH + h)*DD + col4);
        short4 kb;
        kb.x = f2bf(elu1(kq.x)); kb.y = f2bf(elu1(kq.y));
        kb.z = f2bf(elu1(kq.z)); kb.w = f2bf(elu1(kq.w));
        *(short4*)(&Kbh[row][col4 ^ SK(row)]) = kb;
    }

    // ---- Kbh pass-B data (K rows 64..127): load+convert now, LDS-write later
    short4 kbB[2];
#pragma unroll
    for (int it = 0; it < 2; ++it) {
        const int f    = tid + it*512;
        const int row  = 64 + (f >> 4);     // 64..127
        const int col4 = (f & 15) * 4;
        const int s = c*CC + row;
        float4 kq = *(const float4*)(qk + ((((size_t)b*SS + s)*2 + 1)*HH + h)*DD + col4);
        kbB[it].x = f2bf(elu1(kq.x)); kbB[it].y = f2bf(elu1(kq.y));
        kbB[it].z = f2bf(elu1(kq.z)); kbB[it].w = f2bf(elu1(kq.w));
    }

    // ---- prefix record: direct copy into StT (no accumulate) ----
    {
        const short* stp = stp_g + (size_t)blk * RECF;
        short8 st0 = *(const short8*)(stp + tid*8);
        *(short8*)(&StT[tid >> 3][(tid & 7) * 8]) = st0;
        if (tid < 8) {
            short8 st1 = *(const short8*)(stp + 4096 + tid*8);
            *(short8*)(&StT[64][tid * 8]) = st1;
        }
    }

    // ---- Q fragments (elu1 -> bf16) ----
    const int qrow = 16*w + l15;
    const float* qp = qk + ((((size_t)b*SS + (c*CC + qrow))*2 + 0)*HH + h)*DD;
    short8 aq[2];
#pragma unroll
    for (int ks = 0; ks < 2; ++ks) {
        const int k0 = 32*ks + 8*g;
        float4 t0 = *(const float4*)(qp + k0);
        float4 t1 = *(const float4*)(qp + k0 + 4);
        short8 a;
        a[0] = f2bf(elu1(t0.x)); a[1] = f2bf(elu1(t0.y));
        a[2] = f2bf(elu1(t0.z)); a[3] = f2bf(elu1(t0.w));
        a[4] = f2bf(elu1(t1.x)); a[5] = f2bf(elu1(t1.y));
        a[6] = f2bf(elu1(t1.z)); a[7] = f2bf(elu1(t1.w));
        aq[ks] = a;
    }
    __syncthreads();   // sync1: VT, Kbh-A, StT ready

    const int rowb = 16*w + 4*g;

    // ---- S pass A: global cols 0..63 from Kbh (rows 0..63) ----
#pragma unroll
    for (int tc = 0; tc < 4; ++tc) {
        const int kr = 16*tc + l15;
        f32x4 sacc = {0.f,0.f,0.f,0.f};
#pragma unroll
        for (int ks = 0; ks < 2; ++ks) {
            short8 bk = *(const short8*)(&Kbh[kr][(32*ks + 8*g) ^ SK(kr)]);
            sacc = __builtin_amdgcn_mfma_f32_16x16x32_bf16(aq[ks], bk, sacc, 0, 0, 0);
        }
        const int colg = 16*tc + l15;
#pragma unroll
        for (int e = 0; e < 4; ++e) {
            const float sv = (colg <= rowb + e) ? sacc[e] : 0.0f;
            Sbh[rowb + e][colg] = f2bf(sv);
        }
    }
    __syncthreads();   // sync2: Sbh-A ready, Kbh-A reads done

    // ---- Kbh pass-B LDS writes (hidden under the MFMAs below) ----
#pragma unroll
    for (int it = 0; it < 2; ++it) {
        const int f    = tid + it*512;
        const int row  = f >> 4;            // local row 0..63 (global 64..127)
        const int col4 = (f & 15) * 4;
        *(short4*)(&Kbh[row][col4 ^ SK(row)]) = kbB[it];
    }

    // ---- O = S_A.V (kj 0,1) + Q.State^T (kd 0,1); tile 4 = denominator ----
    f32x4 acc[5];
#pragma unroll
    for (int t = 0; t < 5; ++t) acc[t] = (f32x4){0.f,0.f,0.f,0.f};
#pragma unroll
    for (int kj = 0; kj < 2; ++kj) {
        short8 as = *(const short8*)(&Sbh[16*w + l15][32*kj + 8*g]);
#pragma unroll
        for (int tc = 0; tc < 5; ++tc) {
            int vrow = 16*tc + l15;
            if (vrow > 64) vrow = 64;              // clamp into ones row
            short8 bv = *(const short8*)(&VT[vrow][(32*kj + 8*g) ^ SW(vrow)]);
            acc[tc] = __builtin_amdgcn_mfma_f32_16x16x32_bf16(as, bv, acc[tc], 0, 0, 0);
        }
    }
#pragma unroll
    for (int kd = 0; kd < 2; ++kd) {
#pragma unroll
        for (int tc = 0; tc < 5; ++tc) {
            int srow = 16*tc + l15;
            if (srow > 64) srow = 64;              // clamp into ksum row
            short8 bs = *(const short8*)(&StT[srow][32*kd + 8*g]);
            acc[tc] = __builtin_amdgcn_mfma_f32_16x16x32_bf16(aq[kd], bs, acc[tc], 0, 0, 0);
        }
    }
    __syncthreads();   // sync3: Kbh-B visible; Sbh-A reads done

    // ---- S pass B: global cols 64..127 from Kbh (rows 64..127) ----
#pragma unroll
    for (int tc = 4; tc < 8; ++tc) {
        const int kr = 16*(tc-4) + l15;
        f32x4 sacc = {0.f,0.f,0.f,0.f};
#pragma unroll
        for (int ks = 0; ks < 2; ++ks) {
            short8 bk = *(const short8*)(&Kbh[kr][(32*ks + 8*g) ^ SK(kr)]);
            sacc = __builtin_amdgcn_mfma_f32_16x16x32_bf16(aq[ks], bk, sacc, 0, 0, 0);
        }
        const int colg = 16*tc + l15;
#pragma unroll
        for (int e = 0; e < 4; ++e) {
            const float sv = (colg <= rowb + e) ? sacc[e] : 0.0f;
            Sbh[rowb + e][colg - 64] = f2bf(sv);
        }
    }
    __syncthreads();   // sync4: Sbh-B ready

    // ---- O += S_B.V (kj 2,3; global s = 64 + local) ----
#pragma unroll
    for (int kj = 2; kj < 4; ++kj) {
        short8 as = *(const short8*)(&Sbh[16*w + l15][32*(kj-2) + 8*g]);
#pragma unroll
        for (int tc = 0; tc < 5; ++tc) {
            int vrow = 16*tc + l15;
            if (vrow > 64) vrow = 64;
            short8 bv = *(const short8*)(&VT[vrow][(32*kj + 8*g) ^ SW(vrow)]);
            acc[tc] = __builtin_amdgcn_mfma_f32_16x16x32_bf16(as, bv, acc[tc], 0, 0, 0);
        }
    }

    // ---- epilogue: acc[4][e] IS the denominator in every lane ----
    float rn[4];
#pragma unroll
    for (int e = 0; e < 4; ++e) rn[e] = 1.0f / acc[4][e];
    const int rowg = c*CC + rowb;
#pragma unroll
    for (int e = 0; e < 4; ++e) {
        float* orow = out + (((size_t)b*SS + rowg + e)*HH + h)*DD + l15;
#pragma unroll
        for (int tc = 0; tc < 4; ++tc) orow[16*tc] = acc[tc][e] * rn[e];
    }
}

// ---------------------------------------------------------------------------
extern "C" void kernel_launch(void* const* d_in, const int* in_sizes, int n_in,
                              void* d_out, int out_size, void* d_ws, size_t ws_size,
                              hipStream_t stream) {
    const float* qk = (const float*)d_in[0];
    const float* v  = (const float*)d_in[1];
    float* out = (float*)d_out;

    short* rec_g = (short*)d_ws;                   // 512*4160 bf16 = 4.26 MB
    short* stp_g = rec_g + (size_t)NCHK * RECF;    // 512*4160 bf16 = 4.26 MB
    int*   cnt   = (int*)(stp_g + (size_t)NCHK * RECF);   // 32 ints

    hipMemsetAsync(cnt, 0, BHN * sizeof(int), stream);    // graph-safe reset

    k_state<<<dim3(NCHK), dim3(512), 0, stream>>>(qk, v, rec_g, stp_g, cnt);
    k_out  <<<dim3(NCHK), dim3(512), 0, stream>>>(qk, v, stp_g, out);
}

// Round 18
// 30.367 us; speedup vs baseline: 4.9828x; 4.9828x over previous
//
#include <hip/hip_runtime.h>

// Problem constants (B,S,H,D fixed by the reference)
#define BB   2
#define SS   2048
#define HH   16
#define DD   64
#define CC   128               // chunk length
#define NCH  (SS/CC)           // 16 chunks per (b,h)
#define RECF (DD*DD + DD)      // 4160 elems per record: State^T rows 0..63 + ksum row 64
#define BHN  (BB*HH)           // 32
#define NCHK (BHN*NCH)         // 512 chunk-blocks

typedef __attribute__((ext_vector_type(8))) short short8;
typedef __attribute__((ext_vector_type(4))) float f32x4;

// XOR swizzle of the s-index (units of 8 shorts) by LDS row (stride-136 tiles).
#define SW(r) ((((r) >> 3) & 7) << 3)
// XOR swizzle for the pad-free Kbh[64][64] tile in k_out.
#define SK(r) (((r) & 7) << 3)

__device__ __forceinline__ float elu1(float x) {
    return x > 0.0f ? x + 1.0f : __expf(x);
}
__device__ __forceinline__ short f2bf(float f) {
    union { float f; unsigned u; } x; x.f = f;
    unsigned r = x.u + 0x7FFFu + ((x.u >> 16) & 1u);   // RNE
    return (short)(r >> 16);
}
__device__ __forceinline__ float bf2f(short s) {
    union { unsigned u; float f; } x; x.u = ((unsigned)(unsigned short)s) << 16;
    return x.f;
}
// pack two bf16 into one dword: lo -> short[0], hi -> short[1]
__device__ __forceinline__ unsigned pack2(float lo, float hi) {
    return (unsigned)(unsigned short)f2bf(lo)
         | ((unsigned)(unsigned short)f2bf(hi) << 16);
}

// ---------------------------------------------------------------------------
// Kernel 1: per-chunk State^T (+ksum row) = [V^T; ones] . K -> rec_g (bf16).
// 1024 threads/block (VGPR=28 allows 8 waves/SIMD): 2 blocks/CU x 16 waves
// = 32 waves/CU (full occupancy). MFMA work over 16 waves: dtile = w&3,
// rt-group w>>2 (group 0: rt {0, ksum}; groups 1-3: rt 1..3).
// Identical arithmetic + rec layout to R15 (bit-identical output).
// ---------------------------------------------------------------------------
__global__ __launch_bounds__(1024) void k_state(const float* __restrict__ qk,
                                                const float* __restrict__ v,
                                                short* __restrict__ rec_g) {
    const int blk = blockIdx.x;
    const int c   = blk % NCH;
    const int bh  = blk / NCH;
    const int b = bh / HH, h = bh % HH;
    const int tid = threadIdx.x;
    const int w   = tid >> 6;          // 0..15
    const int l   = tid & 63;
    const int l15 = l & 15;
    const int g   = l >> 4;

    __shared__ short KT[64][136];   // K^T, swizzled cols
    __shared__ short VT[65][136];   // V^T + ones row 64

    // packed-pair staging: one item per thread (1024 items total)
    {
        const int pi   = tid;               // 0..1023
        const int r    = pi >> 4;           // row-pair index 0..63
        const int col4 = (pi & 15) * 4;     // d base
        const int s0 = c*CC + 2*r;
        const float* kp = qk + ((((size_t)b*SS + s0)*2 + 1)*HH + h)*DD + col4;
        float4 k0 = *(const float4*)kp;
        float4 k1 = *(const float4*)(kp + 2*HH*DD);
        const float* vp = v + (((size_t)b*SS + s0)*HH + h)*DD + col4;
        float4 v0 = *(const float4*)vp;
        float4 v1 = *(const float4*)(vp + HH*DD);
        const int s2 = 2*r;
        *(unsigned*)(&KT[col4+0][s2 ^ SW(col4+0)]) = pack2(elu1(k0.x), elu1(k1.x));
        *(unsigned*)(&KT[col4+1][s2 ^ SW(col4+1)]) = pack2(elu1(k0.y), elu1(k1.y));
        *(unsigned*)(&KT[col4+2][s2 ^ SW(col4+2)]) = pack2(elu1(k0.z), elu1(k1.z));
        *(unsigned*)(&KT[col4+3][s2 ^ SW(col4+3)]) = pack2(elu1(k0.w), elu1(k1.w));
        *(unsigned*)(&VT[col4+0][s2 ^ SW(col4+0)]) = pack2(v0.x, v1.x);
        *(unsigned*)(&VT[col4+1][s2 ^ SW(col4+1)]) = pack2(v0.y, v1.y);
        *(unsigned*)(&VT[col4+2][s2 ^ SW(col4+2)]) = pack2(v0.z, v1.z);
        *(unsigned*)(&VT[col4+3][s2 ^ SW(col4+3)]) = pack2(v0.w, v1.w);
    }
    if (tid < 64) *(unsigned*)(&VT[64][2*tid]) = 0x3F803F80u;   // ones row (SW(64)==0)
    __syncthreads();

    const int dtile = w & 3;
    const int rtg   = w >> 2;          // 0..3
    const int nrt   = (rtg == 0) ? 2 : 1;
    f32x4 acc1[2];
    acc1[0] = (f32x4){0.f,0.f,0.f,0.f};
    acc1[1] = (f32x4){0.f,0.f,0.f,0.f};
    const int krow = 16*dtile + l15;
#pragma unroll
    for (int ks = 0; ks < 4; ++ks) {
        const int cb = 32*ks + 8*g;
        short8 bk = *(const short8*)(&KT[krow][cb ^ SW(krow)]);
#pragma unroll
        for (int i = 0; i < 2; ++i) {
            if (i < nrt) {
                const int rt = (i == 0) ? rtg : 4;      // rtg0: {0,4}; else {rtg}
                int arow = 16*rt + l15;
                if (arow > 64) arow = 64;               // clamp into ones row
                short8 a = *(const short8*)(&VT[arow][cb ^ SW(arow)]);
                acc1[i] = __builtin_amdgcn_mfma_f32_16x16x32_bf16(a, bk, acc1[i], 0, 0, 0);
            }
        }
    }
    short* rec = rec_g + (size_t)blk * RECF;
#pragma unroll
    for (int i = 0; i < 2; ++i) {
        if (i < nrt) {
            const int rt = (i == 0) ? rtg : 4;
            if (rt < 4) {
#pragma unroll
                for (int e = 0; e < 4; ++e)
                    rec[(16*rt + 4*g + e)*DD + 16*dtile + l15] = f2bf(acc1[i][e]);
            } else if (g == 0) {
                rec[4096 + 16*dtile + l15] = f2bf(acc1[i][0]);   // ksum row
            }
        }
    }
}

// ---------------------------------------------------------------------------
// Kernel 2 (verbatim R15): exclusive prefix scan over chunks (bf16 in/out).
// ---------------------------------------------------------------------------
__global__ __launch_bounds__(256) void k_scan(const short* __restrict__ rec_g,
                                              short* __restrict__ stp_g) {
    const int bh    = blockIdx.x >> 4;
    const int slice = blockIdx.x & 15;
#pragma unroll 1
    for (int ee = threadIdx.x; ee < 260; ee += 256) {
        const int elem = slice*260 + ee;
        float vals[16];
#pragma unroll
        for (int c2 = 0; c2 < 16; ++c2)
            vals[c2] = bf2f(rec_g[(size_t)(bh*NCH + c2)*RECF + elem]);
        float pref = 0.0f;
#pragma unroll
        for (int c2 = 0; c2 < 16; ++c2) {
            stp_g[(size_t)(bh*NCH + c2)*RECF + elem] = f2bf(pref);
            pref += vals[c2];
        }
    }
}

// ---------------------------------------------------------------------------
// Kernel 3 (verbatim R15): O = [S | Q] . [V;ones ; State_prefix^T;ksum].
// Half-K tile staged twice; LDS 53,664 B. No launch-bounds min.
// ---------------------------------------------------------------------------
__global__ __launch_bounds__(512) void k_out(const float* __restrict__ qk,
                                             const float* __restrict__ v,
                                             const short* __restrict__ stp_g,
                                             float* __restrict__ out) {
    const int blk = blockIdx.x;
    const int c   = blk % NCH;
    const int bh  = blk / NCH;
    const int b = bh / HH, h = bh % HH;
    const int tid = threadIdx.x;
    const int w   = tid >> 6;
    const int l   = tid & 63;
    const int l15 = l & 15;
    const int g   = l >> 4;

    __shared__ short Kbh[64][64];   // half K tile, XOR-swizzled   8192 B
    __shared__ short Sbh[128][72];  // score half (two passes)    18432 B
    __shared__ short StT[65][72];   // prefix State^T + ksum row   9360 B
    __shared__ short VT[65][136];   // V^T + ones row 64          17680 B

    // ---- V staging: packed row-pair dword transpose ----
#pragma unroll
    for (int it = 0; it < 2; ++it) {
        const int pi   = tid + it*512;      // 0..1023
        const int r    = pi >> 4;
        const int col4 = (pi & 15) * 4;
        const int s0 = c*CC + 2*r;
        const float* vp = v + (((size_t)b*SS + s0)*HH + h)*DD + col4;
        float4 v0 = *(const float4*)vp;
        float4 v1 = *(const float4*)(vp + HH*DD);
        const int s2 = 2*r;
        *(unsigned*)(&VT[col4+0][s2 ^ SW(col4+0)]) = pack2(v0.x, v1.x);
        *(unsigned*)(&VT[col4+1][s2 ^ SW(col4+1)]) = pack2(v0.y, v1.y);
        *(unsigned*)(&VT[col4+2][s2 ^ SW(col4+2)]) = pack2(v0.z, v1.z);
        *(unsigned*)(&VT[col4+3][s2 ^ SW(col4+3)]) = pack2(v0.w, v1.w);
    }
    if (tid < 64) *(unsigned*)(&VT[64][2*tid]) = 0x3F803F80u;   // ones row

    // ---- Kbh pass-A staging (K rows 0..63) ----
#pragma unroll
    for (int it = 0; it < 2; ++it) {
        const int f    = tid + it*512;      // 0..1023
        const int row  = f >> 4;            // 0..63
        const int col4 = (f & 15) * 4;
        const int s = c*CC + row;
        float4 kq = *(const float4*)(qk + ((((size_t)b*SS + s)*2 + 1)*HH + h)*DD + col4);
        short4 kb;
        kb.x = f2bf(elu1(kq.x)); kb.y = f2bf(elu1(kq.y));
        kb.z = f2bf(elu1(kq.z)); kb.w = f2bf(elu1(kq.w));
        *(short4*)(&Kbh[row][col4 ^ SK(row)]) = kb;
    }

    // ---- Kbh pass-B data (K rows 64..127): load+convert now, LDS-write later
    short4 kbB[2];
#pragma unroll
    for (int it = 0; it < 2; ++it) {
        const int f    = tid + it*512;
        const int row  = 64 + (f >> 4);     // 64..127
        const int col4 = (f & 15) * 4;
        const int s = c*CC + row;
        float4 kq = *(const float4*)(qk + ((((size_t)b*SS + s)*2 + 1)*HH + h)*DD + col4);
        kbB[it].x = f2bf(elu1(kq.x)); kbB[it].y = f2bf(elu1(kq.y));
        kbB[it].z = f2bf(elu1(kq.z)); kbB[it].w = f2bf(elu1(kq.w));
    }

    // ---- prefix record: direct copy into StT (no accumulate) ----
    {
        const short* stp = stp_g + (size_t)blk * RECF;
        short8 st0 = *(const short8*)(stp + tid*8);
        *(short8*)(&StT[tid >> 3][(tid & 7) * 8]) = st0;
        if (tid < 8) {
            short8 st1 = *(const short8*)(stp + 4096 + tid*8);
            *(short8*)(&StT[64][tid * 8]) = st1;
        }
    }

    // ---- Q fragments (elu1 -> bf16) ----
    const int qrow = 16*w + l15;
    const float* qp = qk + ((((size_t)b*SS + (c*CC + qrow))*2 + 0)*HH + h)*DD;
    short8 aq[2];
#pragma unroll
    for (int ks = 0; ks < 2; ++ks) {
        const int k0 = 32*ks + 8*g;
        float4 t0 = *(const float4*)(qp + k0);
        float4 t1 = *(const float4*)(qp + k0 + 4);
        short8 a;
        a[0] = f2bf(elu1(t0.x)); a[1] = f2bf(elu1(t0.y));
        a[2] = f2bf(elu1(t0.z)); a[3] = f2bf(elu1(t0.w));
        a[4] = f2bf(elu1(t1.x)); a[5] = f2bf(elu1(t1.y));
        a[6] = f2bf(elu1(t1.z)); a[7] = f2bf(elu1(t1.w));
        aq[ks] = a;
    }
    __syncthreads();   // sync1: VT, Kbh-A, StT ready

    const int rowb = 16*w + 4*g;

    // ---- S pass A: global cols 0..63 from Kbh (rows 0..63) ----
#pragma unroll
    for (int tc = 0; tc < 4; ++tc) {
        const int kr = 16*tc + l15;
        f32x4 sacc = {0.f,0.f,0.f,0.f};
#pragma unroll
        for (int ks = 0; ks < 2; ++ks) {
            short8 bk = *(const short8*)(&Kbh[kr][(32*ks + 8*g) ^ SK(kr)]);
            sacc = __builtin_amdgcn_mfma_f32_16x16x32_bf16(aq[ks], bk, sacc, 0, 0, 0);
        }
        const int colg = 16*tc + l15;
#pragma unroll
        for (int e = 0; e < 4; ++e) {
            const float sv = (colg <= rowb + e) ? sacc[e] : 0.0f;
            Sbh[rowb + e][colg] = f2bf(sv);
        }
    }
    __syncthreads();   // sync2: Sbh-A ready, Kbh-A reads done

    // ---- Kbh pass-B LDS writes (hidden under the MFMAs below) ----
#pragma unroll
    for (int it = 0; it < 2; ++it) {
        const int f    = tid + it*512;
        const int row  = f >> 4;            // local row 0..63 (global 64..127)
        const int col4 = (f & 15) * 4;
        *(short4*)(&Kbh[row][col4 ^ SK(row)]) = kbB[it];
    }

    // ---- O = S_A.V (kj 0,1) + Q.State^T (kd 0,1); tile 4 = denominator ----
    f32x4 acc[5];
#pragma unroll
    for (int t = 0; t < 5; ++t) acc[t] = (f32x4){0.f,0.f,0.f,0.f};
#pragma unroll
    for (int kj = 0; kj < 2; ++kj) {
        short8 as = *(const short8*)(&Sbh[16*w + l15][32*kj + 8*g]);
#pragma unroll
        for (int tc = 0; tc < 5; ++tc) {
            int vrow = 16*tc + l15;
            if (vrow > 64) vrow = 64;              // clamp into ones row
            short8 bv = *(const short8*)(&VT[vrow][(32*kj + 8*g) ^ SW(vrow)]);
            acc[tc] = __builtin_amdgcn_mfma_f32_16x16x32_bf16(as, bv, acc[tc], 0, 0, 0);
        }
    }
#pragma unroll
    for (int kd = 0; kd < 2; ++kd) {
#pragma unroll
        for (int tc = 0; tc < 5; ++tc) {
            int srow = 16*tc + l15;
            if (srow > 64) srow = 64;              // clamp into ksum row
            short8 bs = *(const short8*)(&StT[srow][32*kd + 8*g]);
            acc[tc] = __builtin_amdgcn_mfma_f32_16x16x32_bf16(aq[kd], bs, acc[tc], 0, 0, 0);
        }
    }
    __syncthreads();   // sync3: Kbh-B visible; Sbh-A reads done

    // ---- S pass B: global cols 64..127 from Kbh (rows 64..127) ----
#pragma unroll
    for (int tc = 4; tc < 8; ++tc) {
        const int kr = 16*(tc-4) + l15;
        f32x4 sacc = {0.f,0.f,0.f,0.f};
#pragma unroll
        for (int ks = 0; ks < 2; ++ks) {
            short8 bk = *(const short8*)(&Kbh[kr][(32*ks + 8*g) ^ SK(kr)]);
            sacc = __builtin_amdgcn_mfma_f32_16x16x32_bf16(aq[ks], bk, sacc, 0, 0, 0);
        }
        const int colg = 16*tc + l15;
#pragma unroll
        for (int e = 0; e < 4; ++e) {
            const float sv = (colg <= rowb + e) ? sacc[e] : 0.0f;
            Sbh[rowb + e][colg - 64] = f2bf(sv);
        }
    }
    __syncthreads();   // sync4: Sbh-B ready

    // ---- O += S_B.V (kj 2,3; global s = 64 + local) ----
#pragma unroll
    for (int kj = 2; kj < 4; ++kj) {
        short8 as = *(const short8*)(&Sbh[16*w + l15][32*(kj-2) + 8*g]);
#pragma unroll
        for (int tc = 0; tc < 5; ++tc) {
            int vrow = 16*tc + l15;
            if (vrow > 64) vrow = 64;
            short8 bv = *(const short8*)(&VT[vrow][(32*kj + 8*g) ^ SW(vrow)]);
            acc[tc] = __builtin_amdgcn_mfma_f32_16x16x32_bf16(as, bv, acc[tc], 0, 0, 0);
        }
    }

    // ---- epilogue: acc[4][e] IS the denominator in every lane ----
    float rn[4];
#pragma unroll
    for (int e = 0; e < 4; ++e) rn[e] = 1.0f / acc[4][e];
    const int rowg = c*CC + rowb;
#pragma unroll
    for (int e = 0; e < 4; ++e) {
        float* orow = out + (((size_t)b*SS + rowg + e)*HH + h)*DD + l15;
#pragma unroll
        for (int tc = 0; tc < 4; ++tc) orow[16*tc] = acc[tc][e] * rn[e];
    }
}

// ---------------------------------------------------------------------------
extern "C" void kernel_launch(void* const* d_in, const int* in_sizes, int n_in,
                              void* d_out, int out_size, void* d_ws, size_t ws_size,
                              hipStream_t stream) {
    const float* qk = (const float*)d_in[0];
    const float* v  = (const float*)d_in[1];
    float* out = (float*)d_out;

    short* rec_g = (short*)d_ws;                   // 512*4160 bf16 = 4.26 MB
    short* stp_g = rec_g + (size_t)NCHK * RECF;    // 512*4160 bf16 = 4.26 MB

    k_state<<<dim3(NCHK), dim3(1024), 0, stream>>>(qk, v, rec_g);
    k_scan <<<dim3(NCHK), dim3(256),  0, stream>>>(rec_g, stp_g);
    k_out  <<<dim3(NCHK), dim3(512),  0, stream>>>(qk, v, stp_g, out);
}